// Round 5
// baseline (43.243 us; speedup 1.0000x reference)
//
#include <hip/hip_runtime.h>
#include <math.h>

#define TT   16384
#define ADIM 1024
#define NCH  1024    // blocks in fused main kernel
#define WPB  4       // waves per block (256 threads)
#define RPW  4       // rows per wave: NCH * WPB * RPW = TT
#define NCH2 64      // second-level context chunks

// fast tanh: 1 - 2/(e^{2x}+1); saturates correctly for large |x|
__device__ __forceinline__ float ftanh(float x) {
    float e2 = __expf(2.0f * x);
    return 1.0f - 2.0f * __builtin_amdgcn_rcpf(e2 + 1.0f);
}

__device__ __forceinline__ float dotrow(const float4* p, const float4* d4, const float4* g4) {
    float dot = 0.f;
#pragma unroll
    for (int j = 0; j < 4; ++j) {
        dot += ftanh(p[j].x + d4[j].x) * g4[j].x;
        dot += ftanh(p[j].y + d4[j].y) * g4[j].y;
        dot += ftanh(p[j].z + d4[j].z) * g4[j].z;
        dot += ftanh(p[j].w + d4[j].w) * g4[j].w;
    }
    return dot;
}

// K1: dec GEMV partials. grid=256, block b handles rows [4b, 4b+4)
__global__ void k1_gemv_part(const float* __restrict__ z, const float* __restrict__ W,
                             float* __restrict__ part) {
    int b = blockIdx.x, tid = threadIdx.x;
    float4 acc = {0.f, 0.f, 0.f, 0.f};
#pragma unroll
    for (int i = 0; i < 4; ++i) {
        int d = b * 4 + i;
        float zv = z[d];
        float4 w4 = reinterpret_cast<const float4*>(W)[(size_t)d * 256 + tid];
        acc.x += zv * w4.x; acc.y += zv * w4.y; acc.z += zv * w4.z; acc.w += zv * w4.w;
    }
    reinterpret_cast<float4*>(part)[(size_t)b * 256 + tid] = acc;
}

// K2: reduce 256 partials -> dp[1024]. grid=64, block b covers cols [16b,16b+16)
__global__ void k2_gemv_red(const float* __restrict__ part, const float* __restrict__ bdec,
                            float* __restrict__ dp) {
    int b = blockIdx.x, tid = threadIdx.x;
    int lane = tid & 63, wv = tid >> 6;
    int rsub = lane >> 2;
    int colg = lane & 3;
    float4 acc = {0.f, 0.f, 0.f, 0.f};
#pragma unroll
    for (int i = 0; i < 4; ++i) {
        int row = i * 64 + wv * 16 + rsub;
        float4 v = reinterpret_cast<const float4*>(part)[(size_t)row * 256 + b * 4 + colg];
        acc.x += v.x; acc.y += v.y; acc.z += v.z; acc.w += v.w;
    }
#pragma unroll
    for (int off = 4; off <= 32; off <<= 1) {
        acc.x += __shfl_xor(acc.x, off, 64);
        acc.y += __shfl_xor(acc.y, off, 64);
        acc.z += __shfl_xor(acc.z, off, 64);
        acc.w += __shfl_xor(acc.w, off, 64);
    }
    __shared__ float4 lds[4][4];
    if (lane < 4) lds[wv][lane] = acc;
    __syncthreads();
    if (tid < 4) {
        float4 t = {0.f, 0.f, 0.f, 0.f};
#pragma unroll
        for (int w = 0; w < 4; ++w) {
            float4 v = lds[w][tid];
            t.x += v.x; t.y += v.y; t.z += v.z; t.w += v.w;
        }
        float4 bd = reinterpret_cast<const float4*>(bdec)[b * 4 + tid];
        t.x += bd.x; t.y += bd.y; t.z += bd.z; t.w += bd.w;
        reinterpret_cast<float4*>(dp)[b * 4 + tid] = t;
    }
}

#define LOADP(BUF, T) do { \
    const float4* _p = reinterpret_cast<const float4*>(pre) + (size_t)(T) * 256; \
    BUF[0] = _p[lane]; BUF[1] = _p[64 + lane]; \
    BUF[2] = _p[128 + lane]; BUF[3] = _p[192 + lane]; } while (0)

#define LOADE(BUF, T) do { \
    const float4* _p = reinterpret_cast<const float4*>(enc) + (size_t)(T) * 256; \
    BUF[0] = _p[lane]; BUF[1] = _p[64 + lane]; \
    BUF[2] = _p[128 + lane]; BUF[3] = _p[192 + lane]; } while (0)

#define ACCE(BUF, PW) do { \
    ca[0].x += (PW) * BUF[0].x; ca[0].y += (PW) * BUF[0].y; \
    ca[0].z += (PW) * BUF[0].z; ca[0].w += (PW) * BUF[0].w; \
    ca[1].x += (PW) * BUF[1].x; ca[1].y += (PW) * BUF[1].y; \
    ca[1].z += (PW) * BUF[1].z; ca[1].w += (PW) * BUF[1].w; \
    ca[2].x += (PW) * BUF[2].x; ca[2].y += (PW) * BUF[2].y; \
    ca[2].z += (PW) * BUF[2].z; ca[2].w += (PW) * BUF[2].w; \
    ca[3].x += (PW) * BUF[3].x; ca[3].y += (PW) * BUF[3].y; \
    ca[3].z += (PW) * BUF[3].z; ca[3].w += (PW) * BUF[3].w; } while (0)

// K3: fused e-score + softmax context partials, software-pipelined streaming.
// grid=NCH x 256. Block b rows [16b,16b+16), wave wv rows t0..t0+3.
__global__ void __launch_bounds__(256) k3_fused(
    const float* __restrict__ pre, const float* __restrict__ enc,
    const float* __restrict__ dp, const float* __restrict__ wg,
    const float* __restrict__ bgp, const float* __restrict__ mask,
    float* __restrict__ e_out, float* __restrict__ m_out,
    float* __restrict__ s_out, float* __restrict__ cpart) {
    int b = blockIdx.x, tid = threadIdx.x;
    int lane = tid & 63, wv = tid >> 6;
    float4 d4[4], g4[4];
    const float4* dp4 = reinterpret_cast<const float4*>(dp);
    const float4* wg4 = reinterpret_cast<const float4*>(wg);
#pragma unroll
    for (int j = 0; j < 4; ++j) { d4[j] = dp4[j * 64 + lane]; g4[j] = wg4[j * 64 + lane]; }
    float bgv = bgp[0];
    int t0 = b * (WPB * RPW) + wv * RPW;

    // Phase A: pipelined dot products over pre (ping-pong A0/A1; loads always in flight)
    float4 A0[4], A1[4];
    float et[RPW];
    LOADP(A0, t0 + 0);
    LOADP(A1, t0 + 1);
    et[0] = dotrow(A0, d4, g4);
    LOADP(A0, t0 + 2);
    et[1] = dotrow(A1, d4, g4);
    LOADP(A1, t0 + 3);
    et[2] = dotrow(A0, d4, g4);
    et[3] = dotrow(A1, d4, g4);

#pragma unroll
    for (int i = 0; i < RPW; ++i) {
#pragma unroll
        for (int off = 32; off; off >>= 1) et[i] += __shfl_xor(et[i], off, 64);
        et[i] = 2.0f * (et[i] + bgv + mask[t0 + i]);
    }
    if (lane == 0) {
#pragma unroll
        for (int i = 0; i < RPW; ++i) e_out[t0 + i] = et[i];
    }

    // Phase B: wave-local max + exps
    float m = fmaxf(fmaxf(et[0], et[1]), fmaxf(et[2], et[3]));
    float p[RPW], s = 0.f;
#pragma unroll
    for (int i = 0; i < RPW; ++i) { p[i] = __expf(et[i] - m); s += p[i]; }

    // Phase C: pipelined weighted accumulation over enc
    float4 ca[4] = {{0,0,0,0},{0,0,0,0},{0,0,0,0},{0,0,0,0}};
    float4 E0[4], E1[4];
    LOADE(E0, t0 + 0);
    LOADE(E1, t0 + 1);
    ACCE(E0, p[0]);
    LOADE(E0, t0 + 2);
    ACCE(E1, p[1]);
    LOADE(E1, t0 + 3);
    ACCE(E0, p[2]);
    ACCE(E1, p[3]);

    // block combine: WPB waves -> one chunk partial
    __shared__ float lm[WPB], ls[WPB];
    __shared__ float4 lc[WPB][256];
#pragma unroll
    for (int j = 0; j < 4; ++j) lc[wv][j * 64 + lane] = ca[j];
    if (lane == 0) { lm[wv] = m; ls[wv] = s; }
    __syncthreads();
    float Mb = fmaxf(fmaxf(lm[0], lm[1]), fmaxf(lm[2], lm[3]));
    float sc[WPB];
#pragma unroll
    for (int w = 0; w < WPB; ++w) sc[w] = __expf(lm[w] - Mb);
    if (tid == 0) {
        float Sb = 0.f;
#pragma unroll
        for (int w = 0; w < WPB; ++w) Sb += ls[w] * sc[w];
        m_out[b] = Mb;
        s_out[b] = Sb;
    }
    float4 o = {0.f, 0.f, 0.f, 0.f};
#pragma unroll
    for (int w = 0; w < WPB; ++w) {
        float4 v = lc[w][tid];
        o.x += sc[w] * v.x; o.y += sc[w] * v.y;
        o.z += sc[w] * v.z; o.w += sc[w] * v.w;
    }
    reinterpret_cast<float4*>(cpart)[(size_t)b * 256 + tid] = o;
}

// K4: global M,S + fold NCH chunk partials -> NCH2. grid=NCH2 blocks.
__global__ void __launch_bounds__(256) k4_fold(
    const float* __restrict__ m_arr, const float* __restrict__ s_arr,
    const float* __restrict__ cpart, float* __restrict__ cpart2,
    float* __restrict__ msout) {
    int b = blockIdx.x, tid = threadIdx.x;
    int lane = tid & 63, wv = tid >> 6;
    __shared__ float redm[4], reds[4];
    float mloc = -3.0e38f;
#pragma unroll
    for (int i = 0; i < NCH / 256; ++i) mloc = fmaxf(mloc, m_arr[tid + i * 256]);
#pragma unroll
    for (int off = 32; off; off >>= 1) mloc = fmaxf(mloc, __shfl_xor(mloc, off, 64));
    if (lane == 0) redm[wv] = mloc;
    __syncthreads();
    float M = fmaxf(fmaxf(redm[0], redm[1]), fmaxf(redm[2], redm[3]));
    float4 acc = {0.f, 0.f, 0.f, 0.f};
#pragma unroll
    for (int i = 0; i < NCH / NCH2; ++i) {
        int r = b * (NCH / NCH2) + i;
        float scf = __expf(m_arr[r] - M);
        float4 v = reinterpret_cast<const float4*>(cpart)[(size_t)r * 256 + tid];
        acc.x += scf * v.x; acc.y += scf * v.y; acc.z += scf * v.z; acc.w += scf * v.w;
    }
    reinterpret_cast<float4*>(cpart2)[(size_t)b * 256 + tid] = acc;
    if (b == 0) {
        float sl = 0.f;
#pragma unroll
        for (int i = 0; i < NCH / 256; ++i)
            sl += s_arr[tid + i * 256] * __expf(m_arr[tid + i * 256] - M);
#pragma unroll
        for (int off = 32; off; off >>= 1) sl += __shfl_xor(sl, off, 64);
        if (lane == 0) reds[wv] = sl;
        __syncthreads();
        if (tid == 0) {
            float S = reds[0] + reds[1] + reds[2] + reds[3];
            msout[0] = M;
            msout[1] = 1.0f / S;
        }
    }
}

// K5: final. blocks 0..15: c columns; blocks 16..31: w = exp(e-M)*invS.
__global__ void __launch_bounds__(256) k5_final(
    const float* __restrict__ cpart2, const float* __restrict__ e,
    const float* __restrict__ ms, float* __restrict__ c_out,
    float* __restrict__ w_out) {
    int b = blockIdx.x, tid = threadIdx.x;
    float M = ms[0], invS = ms[1];
    if (b < 16) {
        int rs = tid >> 4;
        int cg = tid & 15;
        float4 acc = {0.f, 0.f, 0.f, 0.f};
#pragma unroll
        for (int i = 0; i < 4; ++i) {
            int r = rs * 4 + i;
            float4 v = reinterpret_cast<const float4*>(cpart2)[(size_t)r * 256 + b * 16 + cg];
            acc.x += v.x; acc.y += v.y; acc.z += v.z; acc.w += v.w;
        }
        __shared__ float4 lds[16][16];
        lds[rs][cg] = acc;
        __syncthreads();
        if (tid < 16) {
            float4 t = {0.f, 0.f, 0.f, 0.f};
#pragma unroll
            for (int r = 0; r < 16; ++r) {
                float4 v = lds[r][tid];
                t.x += v.x; t.y += v.y; t.z += v.z; t.w += v.w;
            }
            t.x *= invS; t.y *= invS; t.z *= invS; t.w *= invS;
            reinterpret_cast<float4*>(c_out)[b * 16 + tid] = t;
        }
    } else {
        int base = (b - 16) * 256 + tid;
        float4 ev = reinterpret_cast<const float4*>(e)[base];
        float4 w;
        w.x = __expf(ev.x - M) * invS;
        w.y = __expf(ev.y - M) * invS;
        w.z = __expf(ev.z - M) * invS;
        w.w = __expf(ev.w - M) * invS;
        reinterpret_cast<float4*>(w_out)[base] = w;
    }
}

extern "C" void kernel_launch(void* const* d_in, const int* in_sizes, int n_in,
                              void* d_out, int out_size, void* d_ws, size_t ws_size,
                              hipStream_t stream) {
    const float* dec_z = (const float*)d_in[0];
    // d_in[1] = att_prev (unused)
    const float* pre   = (const float*)d_in[2];
    const float* enc   = (const float*)d_in[3];
    const float* mask  = (const float*)d_in[4];
    const float* W_dec = (const float*)d_in[5];
    const float* b_dec = (const float*)d_in[6];
    const float* wg    = (const float*)d_in[7];
    const float* bg    = (const float*)d_in[8];

    float* out   = (float*)d_out;
    float* c_out = out;            // [1024]
    float* w_out = out + ADIM;     // [16384]

    float* ws = (float*)d_ws;
    float* part   = ws;                           // 256*1024
    float* dp     = part + 256 * ADIM;            // 1024
    float* e_sc   = dp + ADIM;                    // 16384
    float* m_arr  = e_sc + TT;                    // NCH
    float* s_arr  = m_arr + NCH;                  // NCH
    float* cpart  = s_arr + NCH;                  // NCH*1024
    float* cpart2 = cpart + (size_t)NCH * ADIM;   // NCH2*1024
    float* ms     = cpart2 + (size_t)NCH2 * ADIM; // 2

    k1_gemv_part<<<256, 256, 0, stream>>>(dec_z, W_dec, part);
    k2_gemv_red<<<64, 256, 0, stream>>>(part, b_dec, dp);
    k3_fused<<<NCH, 256, 0, stream>>>(pre, enc, dp, wg, bg, mask,
                                      e_sc, m_arr, s_arr, cpart);
    k4_fold<<<NCH2, 256, 0, stream>>>(m_arr, s_arr, cpart, cpart2, ms);
    k5_final<<<32, 256, 0, stream>>>(cpart2, e_sc, ms, c_out, w_out);
}

// Round 8
// 40.107 us; speedup vs baseline: 1.0782x; 1.0782x over previous
//
#include <hip/hip_runtime.h>
#include <math.h>

#define TT   16384
#define ADIM 1024
#define NCH  2048    // blocks in fused main kernel (8 rows each)
#define RPB  8       // rows per block
#define NCH2 64      // second-level context chunks

// fast tanh: 1 - 2/(e^{2x}+1); saturates correctly for large |x|
__device__ __forceinline__ float ftanh(float x) {
    float e2 = __expf(2.0f * x);
    return 1.0f - 2.0f * __builtin_amdgcn_rcpf(e2 + 1.0f);
}

__device__ __forceinline__ float pdot(float4 p, float4 d, float4 g) {
    return ftanh(p.x + d.x) * g.x + ftanh(p.y + d.y) * g.y +
           ftanh(p.z + d.z) * g.z + ftanh(p.w + d.w) * g.w;
}

// K1: dec GEMV partials. grid=256, block b handles rows [4b, 4b+4)
__global__ void k1_gemv_part(const float* __restrict__ z, const float* __restrict__ W,
                             float* __restrict__ part) {
    int b = blockIdx.x, tid = threadIdx.x;
    float4 acc = {0.f, 0.f, 0.f, 0.f};
#pragma unroll
    for (int i = 0; i < 4; ++i) {
        int d = b * 4 + i;
        float zv = z[d];
        float4 w4 = reinterpret_cast<const float4*>(W)[(size_t)d * 256 + tid];
        acc.x += zv * w4.x; acc.y += zv * w4.y; acc.z += zv * w4.z; acc.w += zv * w4.w;
    }
    reinterpret_cast<float4*>(part)[(size_t)b * 256 + tid] = acc;
}

// K2: reduce 256 partials -> dp[1024]. grid=64, block b covers cols [16b,16b+16)
__global__ void k2_gemv_red(const float* __restrict__ part, const float* __restrict__ bdec,
                            float* __restrict__ dp) {
    int b = blockIdx.x, tid = threadIdx.x;
    int lane = tid & 63, wv = tid >> 6;
    int rsub = lane >> 2;
    int colg = lane & 3;
    float4 acc = {0.f, 0.f, 0.f, 0.f};
#pragma unroll
    for (int i = 0; i < 4; ++i) {
        int row = i * 64 + wv * 16 + rsub;
        float4 v = reinterpret_cast<const float4*>(part)[(size_t)row * 256 + b * 4 + colg];
        acc.x += v.x; acc.y += v.y; acc.z += v.z; acc.w += v.w;
    }
#pragma unroll
    for (int off = 4; off <= 32; off <<= 1) {
        acc.x += __shfl_xor(acc.x, off, 64);
        acc.y += __shfl_xor(acc.y, off, 64);
        acc.z += __shfl_xor(acc.z, off, 64);
        acc.w += __shfl_xor(acc.w, off, 64);
    }
    __shared__ float4 lds[4][4];
    if (lane < 4) lds[wv][lane] = acc;
    __syncthreads();
    if (tid < 4) {
        float4 t = {0.f, 0.f, 0.f, 0.f};
#pragma unroll
        for (int w = 0; w < 4; ++w) {
            float4 v = lds[w][tid];
            t.x += v.x; t.y += v.y; t.z += v.z; t.w += v.w;
        }
        float4 bd = reinterpret_cast<const float4*>(bdec)[b * 4 + tid];
        t.x += bd.x; t.y += bd.y; t.z += bd.z; t.w += bd.w;
        reinterpret_cast<float4*>(dp)[b * 4 + tid] = t;
    }
}

#define ACC(E, PW) do { \
    ca.x += (PW) * (E).x; ca.y += (PW) * (E).y; \
    ca.z += (PW) * (E).z; ca.w += (PW) * (E).w; } while (0)

// K3: fused e-score + softmax context partials; column-sliced waves.
// grid=NCH x 256. Block b rows [8b, 8b+8). Wave wv owns feature cols
// [256*wv, 256*wv+256) for ALL 8 rows; lane owns one float4 of that slice.
__global__ void __launch_bounds__(256) k3_fused(
    const float* __restrict__ pre, const float* __restrict__ enc,
    const float* __restrict__ dp, const float* __restrict__ wg,
    const float* __restrict__ bgp, const float* __restrict__ mask,
    float* __restrict__ e_out, float* __restrict__ m_out,
    float* __restrict__ s_out, float* __restrict__ cpart) {
    int b = blockIdx.x, tid = threadIdx.x;
    int lane = tid & 63, wv = tid >> 6;
    int col = wv * 64 + lane;   // float4 column index within 256
    float4 d4 = reinterpret_cast<const float4*>(dp)[col];
    float4 g4 = reinterpret_cast<const float4*>(wg)[col];
    float bgv = bgp[0];
    int t0 = b * RPB;
    const float4* pb = reinterpret_cast<const float4*>(pre) + (size_t)t0 * 256 + col;
    const float4* eb = reinterpret_cast<const float4*>(enc) + (size_t)t0 * 256 + col;

    // Phase A: partial dots over this wave's 256-feature slice, 8 rows, ping-pong
    float dt[RPB];
    {
        float4 B0 = pb[0], B1 = pb[256];
        dt[0] = pdot(B0, d4, g4); B0 = pb[512];
        dt[1] = pdot(B1, d4, g4); B1 = pb[768];
        dt[2] = pdot(B0, d4, g4); B0 = pb[1024];
        dt[3] = pdot(B1, d4, g4); B1 = pb[1280];
        dt[4] = pdot(B0, d4, g4); B0 = pb[1536];
        dt[5] = pdot(B1, d4, g4); B1 = pb[1792];
        dt[6] = pdot(B0, d4, g4);
        dt[7] = pdot(B1, d4, g4);
    }
#pragma unroll
    for (int r = 0; r < RPB; ++r) {
#pragma unroll
        for (int off = 32; off; off >>= 1) dt[r] += __shfl_xor(dt[r], off, 64);
    }
    __shared__ float sd[4][RPB];
    if (lane == 0) {
#pragma unroll
        for (int r = 0; r < RPB; ++r) sd[wv][r] = dt[r];
    }
    __syncthreads();
    float et[RPB];
#pragma unroll
    for (int r = 0; r < RPB; ++r)
        et[r] = 2.0f * (sd[0][r] + sd[1][r] + sd[2][r] + sd[3][r] + bgv + mask[t0 + r]);
    if (tid == 0) {
#pragma unroll
        for (int r = 0; r < RPB; ++r) e_out[t0 + r] = et[r];
    }

    // Phase B: block-local softmax pieces (computed redundantly in all threads)
    float m = et[0];
#pragma unroll
    for (int r = 1; r < RPB; ++r) m = fmaxf(m, et[r]);
    float p[RPB], s = 0.f;
#pragma unroll
    for (int r = 0; r < RPB; ++r) { p[r] = __expf(et[r] - m); s += p[r]; }
    if (tid == 0) { m_out[b] = m; s_out[b] = s; }

    // Phase C: weighted accumulation over enc slice, 8 rows, ping-pong
    float4 ca = {0.f, 0.f, 0.f, 0.f};
    {
        float4 E0 = eb[0], E1 = eb[256];
        ACC(E0, p[0]); E0 = eb[512];
        ACC(E1, p[1]); E1 = eb[768];
        ACC(E0, p[2]); E0 = eb[1024];
        ACC(E1, p[3]); E1 = eb[1280];
        ACC(E0, p[4]); E0 = eb[1536];
        ACC(E1, p[5]); E1 = eb[1792];
        ACC(E0, p[6]);
        ACC(E1, p[7]);
    }
    // each wave writes its own disjoint column slice — no cross-wave combine needed
    reinterpret_cast<float4*>(cpart)[(size_t)b * 256 + col] = ca;
}

// K4: global M,S + fold NCH chunk partials -> NCH2. grid=NCH2 blocks.
__global__ void __launch_bounds__(256) k4_fold(
    const float* __restrict__ m_arr, const float* __restrict__ s_arr,
    const float* __restrict__ cpart, float* __restrict__ cpart2,
    float* __restrict__ msout) {
    int b = blockIdx.x, tid = threadIdx.x;
    int lane = tid & 63, wv = tid >> 6;
    __shared__ float redm[4], reds[4];
    float mloc = -3.0e38f;
#pragma unroll
    for (int i = 0; i < NCH / 256; ++i) mloc = fmaxf(mloc, m_arr[tid + i * 256]);
#pragma unroll
    for (int off = 32; off; off >>= 1) mloc = fmaxf(mloc, __shfl_xor(mloc, off, 64));
    if (lane == 0) redm[wv] = mloc;
    __syncthreads();
    float M = fmaxf(fmaxf(redm[0], redm[1]), fmaxf(redm[2], redm[3]));
    float4 acc = {0.f, 0.f, 0.f, 0.f};
#pragma unroll
    for (int i = 0; i < NCH / NCH2; ++i) {
        int r = b * (NCH / NCH2) + i;
        float scf = __expf(m_arr[r] - M);
        float4 v = reinterpret_cast<const float4*>(cpart)[(size_t)r * 256 + tid];
        acc.x += scf * v.x; acc.y += scf * v.y; acc.z += scf * v.z; acc.w += scf * v.w;
    }
    reinterpret_cast<float4*>(cpart2)[(size_t)b * 256 + tid] = acc;
    if (b == 0) {
        float sl = 0.f;
#pragma unroll
        for (int i = 0; i < NCH / 256; ++i)
            sl += s_arr[tid + i * 256] * __expf(m_arr[tid + i * 256] - M);
#pragma unroll
        for (int off = 32; off; off >>= 1) sl += __shfl_xor(sl, off, 64);
        if (lane == 0) reds[wv] = sl;
        __syncthreads();
        if (tid == 0) {
            float S = reds[0] + reds[1] + reds[2] + reds[3];
            msout[0] = M;
            msout[1] = 1.0f / S;
        }
    }
}

// K5: final. blocks 0..15: c columns; blocks 16..31: w = exp(e-M)*invS.
__global__ void __launch_bounds__(256) k5_final(
    const float* __restrict__ cpart2, const float* __restrict__ e,
    const float* __restrict__ ms, float* __restrict__ c_out,
    float* __restrict__ w_out) {
    int b = blockIdx.x, tid = threadIdx.x;
    float M = ms[0], invS = ms[1];
    if (b < 16) {
        int rs = tid >> 4;
        int cg = tid & 15;
        float4 acc = {0.f, 0.f, 0.f, 0.f};
#pragma unroll
        for (int i = 0; i < 4; ++i) {
            int r = rs * 4 + i;
            float4 v = reinterpret_cast<const float4*>(cpart2)[(size_t)r * 256 + b * 16 + cg];
            acc.x += v.x; acc.y += v.y; acc.z += v.z; acc.w += v.w;
        }
        __shared__ float4 lds[16][16];
        lds[rs][cg] = acc;
        __syncthreads();
        if (tid < 16) {
            float4 t = {0.f, 0.f, 0.f, 0.f};
#pragma unroll
            for (int r = 0; r < 16; ++r) {
                float4 v = lds[r][tid];
                t.x += v.x; t.y += v.y; t.z += v.z; t.w += v.w;
            }
            t.x *= invS; t.y *= invS; t.z *= invS; t.w *= invS;
            reinterpret_cast<float4*>(c_out)[b * 16 + tid] = t;
        }
    } else {
        int base = (b - 16) * 256 + tid;
        float4 ev = reinterpret_cast<const float4*>(e)[base];
        float4 w;
        w.x = __expf(ev.x - M) * invS;
        w.y = __expf(ev.y - M) * invS;
        w.z = __expf(ev.z - M) * invS;
        w.w = __expf(ev.w - M) * invS;
        reinterpret_cast<float4*>(w_out)[base] = w;
    }
}

extern "C" void kernel_launch(void* const* d_in, const int* in_sizes, int n_in,
                              void* d_out, int out_size, void* d_ws, size_t ws_size,
                              hipStream_t stream) {
    const float* dec_z = (const float*)d_in[0];
    // d_in[1] = att_prev (unused)
    const float* pre   = (const float*)d_in[2];
    const float* enc   = (const float*)d_in[3];
    const float* mask  = (const float*)d_in[4];
    const float* W_dec = (const float*)d_in[5];
    const float* b_dec = (const float*)d_in[6];
    const float* wg    = (const float*)d_in[7];
    const float* bg    = (const float*)d_in[8];

    float* out   = (float*)d_out;
    float* c_out = out;            // [1024]
    float* w_out = out + ADIM;     // [16384]

    float* ws = (float*)d_ws;
    float* part   = ws;                           // 256*1024
    float* dp     = part + 256 * ADIM;            // 1024
    float* e_sc   = dp + ADIM;                    // 16384
    float* m_arr  = e_sc + TT;                    // NCH
    float* s_arr  = m_arr + NCH;                  // NCH
    float* cpart  = s_arr + NCH;                  // NCH*1024
    float* cpart2 = cpart + (size_t)NCH * ADIM;   // NCH2*1024
    float* ms     = cpart2 + (size_t)NCH2 * ADIM; // 2

    k1_gemv_part<<<256, 256, 0, stream>>>(dec_z, W_dec, part);
    k2_gemv_red<<<64, 256, 0, stream>>>(part, b_dec, dp);
    k3_fused<<<NCH, 256, 0, stream>>>(pre, enc, dp, wg, bg, mask,
                                      e_sc, m_arr, s_arr, cpart);
    k4_fold<<<NCH2, 256, 0, stream>>>(m_arr, s_arr, cpart, cpart2, ms);
    k5_final<<<32, 256, 0, stream>>>(cpart2, e_sc, ms, c_out, w_out);
}

// Round 9
// 39.850 us; speedup vs baseline: 1.0851x; 1.0064x over previous
//
#include <hip/hip_runtime.h>
#include <math.h>

#define TT   16384
#define ADIM 1024
#define NCH  2048    // blocks in fused main kernel (8 rows each)
#define RPB  8       // rows per block
#define NCH2 128     // second-level context chunks (fold 16 each)

// fast tanh: 1 - 2/(e^{2x}+1); saturates correctly for large |x|
__device__ __forceinline__ float ftanh(float x) {
    float e2 = __expf(2.0f * x);
    return 1.0f - 2.0f * __builtin_amdgcn_rcpf(e2 + 1.0f);
}

__device__ __forceinline__ float pdot(float4 p, float4 d, float4 g) {
    return ftanh(p.x + d.x) * g.x + ftanh(p.y + d.y) * g.y +
           ftanh(p.z + d.z) * g.z + ftanh(p.w + d.w) * g.w;
}

// K1: dec GEMV partials. grid=256, block b handles rows [4b, 4b+4)
__global__ void k1_gemv_part(const float* __restrict__ z, const float* __restrict__ W,
                             float* __restrict__ part) {
    int b = blockIdx.x, tid = threadIdx.x;
    float4 acc = {0.f, 0.f, 0.f, 0.f};
#pragma unroll
    for (int i = 0; i < 4; ++i) {
        int d = b * 4 + i;
        float zv = z[d];
        float4 w4 = reinterpret_cast<const float4*>(W)[(size_t)d * 256 + tid];
        acc.x += zv * w4.x; acc.y += zv * w4.y; acc.z += zv * w4.z; acc.w += zv * w4.w;
    }
    reinterpret_cast<float4*>(part)[(size_t)b * 256 + tid] = acc;
}

// K2: reduce 256 partials -> dp[1024]. grid=64, block b covers cols [16b,16b+16)
__global__ void k2_gemv_red(const float* __restrict__ part, const float* __restrict__ bdec,
                            float* __restrict__ dp) {
    int b = blockIdx.x, tid = threadIdx.x;
    int lane = tid & 63, wv = tid >> 6;
    int rsub = lane >> 2;
    int colg = lane & 3;
    float4 acc = {0.f, 0.f, 0.f, 0.f};
#pragma unroll
    for (int i = 0; i < 4; ++i) {
        int row = i * 64 + wv * 16 + rsub;
        float4 v = reinterpret_cast<const float4*>(part)[(size_t)row * 256 + b * 4 + colg];
        acc.x += v.x; acc.y += v.y; acc.z += v.z; acc.w += v.w;
    }
#pragma unroll
    for (int off = 4; off <= 32; off <<= 1) {
        acc.x += __shfl_xor(acc.x, off, 64);
        acc.y += __shfl_xor(acc.y, off, 64);
        acc.z += __shfl_xor(acc.z, off, 64);
        acc.w += __shfl_xor(acc.w, off, 64);
    }
    __shared__ float4 lds[4][4];
    if (lane < 4) lds[wv][lane] = acc;
    __syncthreads();
    if (tid < 4) {
        float4 t = {0.f, 0.f, 0.f, 0.f};
#pragma unroll
        for (int w = 0; w < 4; ++w) {
            float4 v = lds[w][tid];
            t.x += v.x; t.y += v.y; t.z += v.z; t.w += v.w;
        }
        float4 bd = reinterpret_cast<const float4*>(bdec)[b * 4 + tid];
        t.x += bd.x; t.y += bd.y; t.z += bd.z; t.w += bd.w;
        reinterpret_cast<float4*>(dp)[b * 4 + tid] = t;
    }
}

// K3: fused e-score + softmax context partials; column-sliced waves, max MLP.
// grid=NCH x 256. Block b rows [8b, 8b+8). Wave wv owns feature cols
// [256*wv, 256*wv+256) for ALL 8 rows; lane owns one float4 of that slice.
// All 16 row-loads (8 pre + 8 enc) are issued up front -> 16KB in flight/wave;
// enc rows stay in registers, phase C is pure FMA.
__global__ void __launch_bounds__(256) k3_fused(
    const float* __restrict__ pre, const float* __restrict__ enc,
    const float* __restrict__ dp, const float* __restrict__ wg,
    const float* __restrict__ bgp, const float* __restrict__ mask,
    float* __restrict__ e_out, float* __restrict__ m_out,
    float* __restrict__ s_out, float* __restrict__ cpart) {
    int b = blockIdx.x, tid = threadIdx.x;
    int lane = tid & 63, wv = tid >> 6;
    int col = wv * 64 + lane;   // float4 column index within 256
    float4 d4 = reinterpret_cast<const float4*>(dp)[col];
    float4 g4 = reinterpret_cast<const float4*>(wg)[col];
    float bgv = bgp[0];
    int t0 = b * RPB;
    const float4* pb = reinterpret_cast<const float4*>(pre) + (size_t)t0 * 256 + col;
    const float4* eb = reinterpret_cast<const float4*>(enc) + (size_t)t0 * 256 + col;

    // Issue ALL loads up front: 16 independent dwordx4 per lane in flight.
    float4 pv[RPB], ev[RPB];
#pragma unroll
    for (int r = 0; r < RPB; ++r) pv[r] = pb[r * 256];
#pragma unroll
    for (int r = 0; r < RPB; ++r) ev[r] = eb[r * 256];

    // Phase A: partial dots over this wave's 256-feature slice
    float dt[RPB];
#pragma unroll
    for (int r = 0; r < RPB; ++r) dt[r] = pdot(pv[r], d4, g4);
#pragma unroll
    for (int r = 0; r < RPB; ++r) {
#pragma unroll
        for (int off = 32; off; off >>= 1) dt[r] += __shfl_xor(dt[r], off, 64);
    }
    __shared__ float sd[4][RPB];
    if (lane == 0) {
#pragma unroll
        for (int r = 0; r < RPB; ++r) sd[wv][r] = dt[r];
    }
    __syncthreads();
    float et[RPB];
#pragma unroll
    for (int r = 0; r < RPB; ++r)
        et[r] = 2.0f * (sd[0][r] + sd[1][r] + sd[2][r] + sd[3][r] + bgv + mask[t0 + r]);
    if (tid == 0) {
#pragma unroll
        for (int r = 0; r < RPB; ++r) e_out[t0 + r] = et[r];
    }

    // Phase B: block-local softmax pieces (computed redundantly in all threads)
    float m = et[0];
#pragma unroll
    for (int r = 1; r < RPB; ++r) m = fmaxf(m, et[r]);
    float p[RPB], s = 0.f;
#pragma unroll
    for (int r = 0; r < RPB; ++r) { p[r] = __expf(et[r] - m); s += p[r]; }
    if (tid == 0) { m_out[b] = m; s_out[b] = s; }

    // Phase C: weighted accumulation from registers (no memory traffic)
    float4 ca = {0.f, 0.f, 0.f, 0.f};
#pragma unroll
    for (int r = 0; r < RPB; ++r) {
        ca.x += p[r] * ev[r].x; ca.y += p[r] * ev[r].y;
        ca.z += p[r] * ev[r].z; ca.w += p[r] * ev[r].w;
    }
    // each wave writes its own disjoint column slice — no cross-wave combine needed
    reinterpret_cast<float4*>(cpart)[(size_t)b * 256 + col] = ca;
}

// K4: global M,S + fold NCH chunk partials -> NCH2. grid=NCH2 blocks.
__global__ void __launch_bounds__(256) k4_fold(
    const float* __restrict__ m_arr, const float* __restrict__ s_arr,
    const float* __restrict__ cpart, float* __restrict__ cpart2,
    float* __restrict__ msout) {
    int b = blockIdx.x, tid = threadIdx.x;
    int lane = tid & 63, wv = tid >> 6;
    __shared__ float redm[4], reds[4];
    float mloc = -3.0e38f;
#pragma unroll
    for (int i = 0; i < NCH / 256; ++i) mloc = fmaxf(mloc, m_arr[tid + i * 256]);
#pragma unroll
    for (int off = 32; off; off >>= 1) mloc = fmaxf(mloc, __shfl_xor(mloc, off, 64));
    if (lane == 0) redm[wv] = mloc;
    __syncthreads();
    float M = fmaxf(fmaxf(redm[0], redm[1]), fmaxf(redm[2], redm[3]));
    float4 acc = {0.f, 0.f, 0.f, 0.f};
#pragma unroll
    for (int i = 0; i < NCH / NCH2; ++i) {
        int r = b * (NCH / NCH2) + i;
        float scf = __expf(m_arr[r] - M);
        float4 v = reinterpret_cast<const float4*>(cpart)[(size_t)r * 256 + tid];
        acc.x += scf * v.x; acc.y += scf * v.y; acc.z += scf * v.z; acc.w += scf * v.w;
    }
    reinterpret_cast<float4*>(cpart2)[(size_t)b * 256 + tid] = acc;
    if (b == 0) {
        float sl = 0.f;
#pragma unroll
        for (int i = 0; i < NCH / 256; ++i)
            sl += s_arr[tid + i * 256] * __expf(m_arr[tid + i * 256] - M);
#pragma unroll
        for (int off = 32; off; off >>= 1) sl += __shfl_xor(sl, off, 64);
        if (lane == 0) reds[wv] = sl;
        __syncthreads();
        if (tid == 0) {
            float S = reds[0] + reds[1] + reds[2] + reds[3];
            msout[0] = M;
            msout[1] = 1.0f / S;
        }
    }
}

// K5: final. blocks 0..15: c columns; blocks 16..31: w = exp(e-M)*invS.
__global__ void __launch_bounds__(256) k5_final(
    const float* __restrict__ cpart2, const float* __restrict__ e,
    const float* __restrict__ ms, float* __restrict__ c_out,
    float* __restrict__ w_out) {
    int b = blockIdx.x, tid = threadIdx.x;
    float M = ms[0], invS = ms[1];
    if (b < 16) {
        int rs = tid >> 4;   // 0..15 row-groups
        int cg = tid & 15;   // float4 group within block's 64 cols
        float4 acc = {0.f, 0.f, 0.f, 0.f};
#pragma unroll
        for (int i = 0; i < NCH2 / 16; ++i) {
            int r = rs * (NCH2 / 16) + i;
            float4 v = reinterpret_cast<const float4*>(cpart2)[(size_t)r * 256 + b * 16 + cg];
            acc.x += v.x; acc.y += v.y; acc.z += v.z; acc.w += v.w;
        }
        __shared__ float4 lds[16][16];
        lds[rs][cg] = acc;
        __syncthreads();
        if (tid < 16) {
            float4 t = {0.f, 0.f, 0.f, 0.f};
#pragma unroll
            for (int r = 0; r < 16; ++r) {
                float4 v = lds[r][tid];
                t.x += v.x; t.y += v.y; t.z += v.z; t.w += v.w;
            }
            t.x *= invS; t.y *= invS; t.z *= invS; t.w *= invS;
            reinterpret_cast<float4*>(c_out)[b * 16 + tid] = t;
        }
    } else {
        int base = (b - 16) * 256 + tid;
        float4 ev = reinterpret_cast<const float4*>(e)[base];
        float4 w;
        w.x = __expf(ev.x - M) * invS;
        w.y = __expf(ev.y - M) * invS;
        w.z = __expf(ev.z - M) * invS;
        w.w = __expf(ev.w - M) * invS;
        reinterpret_cast<float4*>(w_out)[base] = w;
    }
}

extern "C" void kernel_launch(void* const* d_in, const int* in_sizes, int n_in,
                              void* d_out, int out_size, void* d_ws, size_t ws_size,
                              hipStream_t stream) {
    const float* dec_z = (const float*)d_in[0];
    // d_in[1] = att_prev (unused)
    const float* pre   = (const float*)d_in[2];
    const float* enc   = (const float*)d_in[3];
    const float* mask  = (const float*)d_in[4];
    const float* W_dec = (const float*)d_in[5];
    const float* b_dec = (const float*)d_in[6];
    const float* wg    = (const float*)d_in[7];
    const float* bg    = (const float*)d_in[8];

    float* out   = (float*)d_out;
    float* c_out = out;            // [1024]
    float* w_out = out + ADIM;     // [16384]

    float* ws = (float*)d_ws;
    float* part   = ws;                           // 256*1024
    float* dp     = part + 256 * ADIM;            // 1024
    float* e_sc   = dp + ADIM;                    // 16384
    float* m_arr  = e_sc + TT;                    // NCH
    float* s_arr  = m_arr + NCH;                  // NCH
    float* cpart  = s_arr + NCH;                  // NCH*1024
    float* cpart2 = cpart + (size_t)NCH * ADIM;   // NCH2*1024
    float* ms     = cpart2 + (size_t)NCH2 * ADIM; // 2

    k1_gemv_part<<<256, 256, 0, stream>>>(dec_z, W_dec, part);
    k2_gemv_red<<<64, 256, 0, stream>>>(part, b_dec, dp);
    k3_fused<<<NCH, 256, 0, stream>>>(pre, enc, dp, wg, bg, mask,
                                      e_sc, m_arr, s_arr, cpart);
    k4_fold<<<NCH2, 256, 0, stream>>>(m_arr, s_arr, cpart, cpart2, ms);
    k5_final<<<32, 256, 0, stream>>>(cpart2, e_sc, ms, c_out, w_out);
}